// Round 18
// baseline (79.069 us; speedup 1.0000x reference)
//
#include <hip/hip_runtime.h>

// CMDNet (M=2, m={-1,+1}, equal alpha) — MFMA HH + dot2/DPP matvec.
// = R17 kernel with ONE change: __launch_bounds__(256) — NO waves/EU arg.
//
// R17 post-mortem (the real occupancy story): occupancy sat at ~36% for
// every (256,4) build regardless of resources (R4: 3KB LDS + 56 VGPR,
// still 37.7%), and jumped to 65-80% for every (256,8) build. The second
// launch_bounds arg on this toolchain emits amdgpu-waves-per-eu as a
// RESIDENCY CAP (min treated as max), not just an allocator hint. Drop it:
// allocator unconstrained (~60 VGPR + 16 AGPR = 76 total -> 6 waves/SIMD),
// LDS 18.4KB -> 8 blocks/CU. Residency now limited by true resources only.
//
// Numerics (proven R10-R17, absmax = bf16 output quantum): bf16 hi/lo MFMA
// HH (~2^-17), f16 HH LDS store (0.5-prefolded), dot2-f16 matvec,
// permlane16_swap xor-16 ((A+B)-x recovery), exp2-domain G, tanh epilogue.
// Tripwire: FETCH >> 68 MB or WRITE >> 6 MB => spill => restore (256,4).

#define NRX 64
#define KSYM 32

typedef float  f32x16 __attribute__((ext_vector_type(16)));
typedef short  short8 __attribute__((ext_vector_type(8)));
typedef _Float16 h16x2 __attribute__((ext_vector_type(2)));

__device__ __forceinline__ float readlane_f(float v, int lane) {
    return __int_as_float(__builtin_amdgcn_readlane(__float_as_int(v), lane));
}
__device__ __forceinline__ unsigned cvt_pk_bf16(float a, float b) {
    unsigned r;
    asm("v_cvt_pk_bf16_f32 %0, %1, %2" : "=v"(r) : "v"(a), "v"(b));
    return r;
}
__device__ __forceinline__ int cvt_pk_f16(float a, float b) {  // RTZ pack
    int r;
    asm("v_cvt_pkrtz_f16_f32 %0, %1, %2" : "=v"(r) : "v"(a), "v"(b));
    return r;
}
// ONE-instruction DPP rotate. J must be a literal. dst write-only (R9 audit).
#define DPP_ROR(DST, SRC, J)                                                   \
    asm("v_mov_b32_dpp %0, %1 row_ror:" #J " row_mask:0xf bank_mask:0xf"       \
        : "=v"(DST) : "v"(SRC))

__device__ __forceinline__ float dot2_f16(int a, int b, float c) {
#if __has_builtin(__builtin_amdgcn_fdot2)
    union { int i; h16x2 h; } ua, ub;
    ua.i = a; ub.i = b;
    return __builtin_amdgcn_fdot2(ua.h, ub.h, c, false);
#else
    float r = c;
    asm("v_dot2_f32_f16 %0, %1, %2, %0" : "+v"(r) : "v"(a), "v"(b));
    return r;
#endif
}
__device__ __forceinline__ float exp2_fast(float x) {
#if __has_builtin(__builtin_amdgcn_exp2f)
    return __builtin_amdgcn_exp2f(x);
#else
    float r; asm("v_exp_f32 %0, %1" : "=v"(r) : "v"(x)); return r;
#endif
}
__device__ __forceinline__ float xor16_f(float x) {
#if __has_builtin(__builtin_amdgcn_permlane16_swap)
    typedef unsigned uint2v __attribute__((ext_vector_type(2)));
    unsigned xi = __float_as_int(x);
    uint2v pr = __builtin_amdgcn_permlane16_swap(xi, xi, false, false);
    return (__uint_as_float(pr[0]) + __uint_as_float(pr[1])) - x;
#else
    return __int_as_float(
        __builtin_amdgcn_ds_swizzle(__float_as_int(x), 0x401F)); // xor 16
#endif
}

union FragU { unsigned u[4]; short8 s; };

__global__ __launch_bounds__(256) void cmdnet_kernel(
    const float* __restrict__ yt,      // [B,64]
    const float* __restrict__ Ht,      // [B,64,32]
    const float* __restrict__ sigmat0, // [B]
    const float* __restrict__ taui,    // [niter+1]
    const float* __restrict__ delta,   // [niter]
    float* __restrict__ out_ft,        // [B,32,2]
    float* __restrict__ out_xt,        // [B,32]
    int niter)
{
    __shared__ __align__(16) _Float16 hh16[4][2][KSYM * KSYM]; // 16 KB (2KB/region)
    __shared__ __align__(16) float    ytL[4][2][NRX];          // 2 KB

    const int tid  = threadIdx.x;
    const int w    = tid >> 6;
    const int lane = tid & 63;
    const int k    = lane & 31;
    const int h    = lane >> 5;
    const int hi8  = h * 8;
    const int bb   = blockIdx.x * 8 + w * 2;
    const int b    = bb + h;
    const float LOG2E = 1.4426950408889634f;

    ytL[w][0][lane] = yt[(size_t)bb * NRX + lane];
    ytL[w][1][lane] = yt[(size_t)bb * NRX + NRX + lane];

    // delta in exp2 domain; tau natural
    float dreg = 0.f, treg = 1.f;
    if (lane < niter) { dreg = delta[lane] * LOG2E; treg = fabsf(taui[lane + 1]); }

    float sig2 = sigmat0[b];
    sig2 *= sig2;

    float yhp0 = 0.f, yhp1 = 0.f;

    // ---- Phase 1: per batch s: MFMA HH (f[8] staging in flight) ----
    #pragma unroll
    for (int s = 0; s < 2; ++s) {
        f32x16 acc;
        #pragma unroll
        for (int j = 0; j < 16; ++j) acc[j] = 0.f;

        const float* Hb = Ht + ((size_t)(bb + s)) * (NRX * KSYM);
        #pragma unroll
        for (int c = 0; c < 4; ++c) {
            const float* base = Hb + (c * 16 + hi8) * KSYM + k;
            float f[8];
            #pragma unroll
            for (int e = 0; e < 8; ++e) f[e] = base[e * KSYM];

            float4 ya = *reinterpret_cast<const float4*>(&ytL[w][s][c * 16 + hi8]);
            float4 yb = *reinterpret_cast<const float4*>(&ytL[w][s][c * 16 + hi8 + 4]);
            float yp = (s == 0) ? yhp0 : yhp1;
            yp = fmaf(ya.x, f[0], yp); yp = fmaf(ya.y, f[1], yp);
            yp = fmaf(ya.z, f[2], yp); yp = fmaf(ya.w, f[3], yp);
            yp = fmaf(yb.x, f[4], yp); yp = fmaf(yb.y, f[5], yp);
            yp = fmaf(yb.z, f[6], yp); yp = fmaf(yb.w, f[7], yp);
            if (s == 0) yhp0 = yp; else yhp1 = yp;

            FragU hiF, loF;
            #pragma unroll
            for (int p = 0; p < 4; ++p) {
                unsigned hp = cvt_pk_bf16(f[2*p], f[2*p+1]);
                float h0 = __uint_as_float(hp << 16);
                float h1 = __uint_as_float(hp & 0xffff0000u);
                loF.u[p] = cvt_pk_bf16(f[2*p] - h0, f[2*p+1] - h1);
                hiF.u[p] = hp;
            }
            acc = __builtin_amdgcn_mfma_f32_32x32x16_bf16(hiF.s, hiF.s, acc, 0, 0, 0);
            acc = __builtin_amdgcn_mfma_f32_32x32x16_bf16(hiF.s, loF.s, acc, 0, 0, 0);
            acc = __builtin_amdgcn_mfma_f32_32x32x16_bf16(loF.s, hiF.s, acc, 0, 0, 0);
        }

        // acc -> f16 LDS (0.5-prefolded). C/D layout: col=k, row=(j&3)+8*(j>>2)+4*h
        #pragma unroll
        for (int j = 0; j < 16; ++j) {
            int row = (j & 3) + 8 * (j >> 2) + 4 * h;
            hh16[w][s][row * 32 + k] = (_Float16)(0.5f * acc[j]);
        }
    }

    // ---- Phase 2: UNIFORM gather from region h (same DPP_ROR as loop) ----
    int own_pk[16];
    {
        const int low4 = k & 15;
        const unsigned short* rp =
            reinterpret_cast<const unsigned short*>(&hh16[w][h][0]) + k * 32;
        own_pk[0] = (int)rp[k] | ((int)rp[k ^ 16] << 16);
        #define GATH(J) { \
            int idx; DPP_ROR(idx, low4, J); \
            int cA = (k & 16) | idx; \
            own_pk[J] = (int)rp[cA] | ((int)rp[cA ^ 16] << 16); }
        GATH(1)  GATH(2)  GATH(3)  GATH(4)  GATH(5)
        GATH(6)  GATH(7)  GATH(8)  GATH(9)  GATH(10)
        GATH(11) GATH(12) GATH(13) GATH(14) GATH(15)
        #undef GATH
    }

    float yh0 = yhp0 + __shfl_xor(yhp0, 32, 64);
    float yh1 = yhp1 + __shfl_xor(yhp1, 32, 64);
    float yh  = 0.5f * (h ? yh1 : yh0);   // pre-halved to match own_pk scale

    // ---- Phase 3: iterations ----
    float tau = fabsf(taui[0]);
    float Gl0 = 0.f, Gl1 = 0.f;           // G * log2e
    float xt = 0.f;

    for (int i = 0; i < niter; ++i) {
        float d2       = readlane_f(dreg, i);   // delta*log2e
        float tau_next = readlane_f(treg, i);

        float e0 = exp2_fast(-Gl0);        // = exp(-G0), prev-iter dep only
        float e1 = exp2_fast(-Gl1);

        float xts = xor16_f(xt);
        int xpk = cvt_pk_f16(xt, xts);

        float a0 = -yh, a1 = 0.f, a2 = 0.f, a3 = 0.f;
        a0 = dot2_f16(own_pk[0], xpk, a0);
        #define STEP(J) {                                                      \
            int xr; DPP_ROR(xr, xpk, J);                                       \
            float& aa = ((J) & 3) == 0 ? a0 : ((J) & 3) == 1 ? a1              \
                       : ((J) & 3) == 2 ? a2 : a3;                             \
            aa = dot2_f16(own_pk[J], xr, aa); }
        STEP(1)  STEP(2)  STEP(3)  STEP(4)  STEP(5)
        STEP(6)  STEP(7)  STEP(8)  STEP(9)  STEP(10)
        STEP(11) STEP(12) STEP(13) STEP(14) STEP(15)
        #undef STEP
        float r = (a0 + a1) + (a2 + a3);   // = 0.5*(xHH - yH)

        float t  = fmaf(-xt, xt, 1.0f);
        float p  = tau * t * r;            // = 2*tau*ft0*ft1*(xHH-yH)
        float g0 = fmaf(sig2, 1.f - e0, -p);
        float g1 = fmaf(sig2, 1.f - e1,  p);
        Gl0 = fmaf(-d2, g0, Gl0);
        Gl1 = fmaf(-d2, g1, Gl1);

        tau = tau_next;
        float z2 = tau * (Gl1 - Gl0);      // = log2e * z
        float ez = exp2_fast(-fabsf(z2));  // = exp(-|z|)
        float sg = __builtin_amdgcn_rcpf(1.f + ez);
        float m  = (1.f - ez) * sg;        // |tanh(z/2)|
        xt = __builtin_copysignf(m, z2);
    }

    // ---- outputs: ft1 = (1+xt)/2, ft0 = (1-xt)/2 ----
    float ft1 = fmaf(0.5f, xt, 0.5f);
    float ft0 = 1.f - ft1;
    float2 f2 = make_float2(ft0, ft1);
    reinterpret_cast<float2*>(out_ft)[(size_t)b * KSYM + k] = f2;
    out_xt[(size_t)b * KSYM + k] = xt;
}

extern "C" void kernel_launch(void* const* d_in, const int* in_sizes, int n_in,
                              void* d_out, int out_size, void* d_ws, size_t ws_size,
                              hipStream_t stream) {
    const float* yt    = (const float*)d_in[0];
    const float* Ht    = (const float*)d_in[1];
    const float* sg    = (const float*)d_in[2];
    const float* taui  = (const float*)d_in[3];
    const float* delta = (const float*)d_in[4];
    int B     = in_sizes[2];
    int niter = in_sizes[4];
    float* out    = (float*)d_out;
    float* out_ft = out;
    float* out_xt = out + (size_t)B * 64;

    dim3 grid(B / 8), block(256);
    hipLaunchKernelGGL(cmdnet_kernel, grid, block, 0, stream,
                       yt, Ht, sg, taui, delta, out_ft, out_xt, niter);
}

// Round 19
// 77.318 us; speedup vs baseline: 1.0227x; 1.0227x over previous
//
#include <hip/hip_runtime.h>

// CMDNet (M=2, m={-1,+1}, equal alpha) — MFMA HH + dot2/DPP matvec.
// Plateau-refinement round: R14/R17/R18 are one plateau (77-79us).
// Residency is exhausted (6 occupancy asks, ILP, split: all <= neutral);
// loop-region VALU util ~75-85% => compute-bound => cut instructions:
//  1. xor16 partner via ONE v_cndmask on permlane16_swap outputs
//     (pr0 = even-rows-dup, pr1 = odd-rows-dup; partner = hi16?pr0:pr1).
//     Exact, -1 instr, -1 chain step vs (A+B)-x.
//  2. e = exp2(-G) computed right after each G-update for the NEXT iter
//     (trans ops hide under the next matvec instead of heading the chain).
//  3. iteration loop unrolled x2 (even/odd bodies, odd-niter guard).
// Everything else = R17: f16 HH LDS (18.4KB), (256,4), proven numerics
// (bf16 hi/lo MFMA HH ~2^-17, dot2-f16 matvec 0.5-prefolded,
//  exp2-domain G, tanh epilogue; absmax = bf16 output quantum).
// Tripwire: FETCH >> 68 MB or WRITE >> 6 MB => spill => revert to R14.

#define NRX 64
#define KSYM 32

typedef float  f32x16 __attribute__((ext_vector_type(16)));
typedef short  short8 __attribute__((ext_vector_type(8)));
typedef _Float16 h16x2 __attribute__((ext_vector_type(2)));

__device__ __forceinline__ float readlane_f(float v, int lane) {
    return __int_as_float(__builtin_amdgcn_readlane(__float_as_int(v), lane));
}
__device__ __forceinline__ unsigned cvt_pk_bf16(float a, float b) {
    unsigned r;
    asm("v_cvt_pk_bf16_f32 %0, %1, %2" : "=v"(r) : "v"(a), "v"(b));
    return r;
}
__device__ __forceinline__ int cvt_pk_f16(float a, float b) {  // RTZ pack
    int r;
    asm("v_cvt_pkrtz_f16_f32 %0, %1, %2" : "=v"(r) : "v"(a), "v"(b));
    return r;
}
// ONE-instruction DPP rotate. J must be a literal. dst write-only (R9 audit).
#define DPP_ROR(DST, SRC, J)                                                   \
    asm("v_mov_b32_dpp %0, %1 row_ror:" #J " row_mask:0xf bank_mask:0xf"       \
        : "=v"(DST) : "v"(SRC))

__device__ __forceinline__ float dot2_f16(int a, int b, float c) {
#if __has_builtin(__builtin_amdgcn_fdot2)
    union { int i; h16x2 h; } ua, ub;
    ua.i = a; ub.i = b;
    return __builtin_amdgcn_fdot2(ua.h, ub.h, c, false);
#else
    float r = c;
    asm("v_dot2_f32_f16 %0, %1, %2, %0" : "+v"(r) : "v"(a), "v"(b));
    return r;
#endif
}
__device__ __forceinline__ float exp2_fast(float x) {
#if __has_builtin(__builtin_amdgcn_exp2f)
    return __builtin_amdgcn_exp2f(x);
#else
    float r; asm("v_exp_f32 %0, %1" : "=v"(r) : "v"(x)); return r;
#endif
}
// partner at lane^16: pr0 = even-16-rows duplicated, pr1 = odd-16-rows dup;
// partner = (lane&16) ? pr0 : pr1  — one cndmask, exact.
__device__ __forceinline__ float xor16_f(float x, bool hi16) {
#if __has_builtin(__builtin_amdgcn_permlane16_swap)
    typedef unsigned uint2v __attribute__((ext_vector_type(2)));
    unsigned xi = __float_as_int(x);
    uint2v pr = __builtin_amdgcn_permlane16_swap(xi, xi, false, false);
    return hi16 ? __uint_as_float(pr[0]) : __uint_as_float(pr[1]);
#else
    (void)hi16;
    return __int_as_float(
        __builtin_amdgcn_ds_swizzle(__float_as_int(x), 0x401F)); // xor 16
#endif
}

union FragU { unsigned u[4]; short8 s; };

__global__ __launch_bounds__(256, 4) void cmdnet_kernel(
    const float* __restrict__ yt,      // [B,64]
    const float* __restrict__ Ht,      // [B,64,32]
    const float* __restrict__ sigmat0, // [B]
    const float* __restrict__ taui,    // [niter+1]
    const float* __restrict__ delta,   // [niter]
    float* __restrict__ out_ft,        // [B,32,2]
    float* __restrict__ out_xt,        // [B,32]
    int niter)
{
    __shared__ __align__(16) _Float16 hh16[4][2][KSYM * KSYM]; // 16 KB (2KB/region)
    __shared__ __align__(16) float    ytL[4][2][NRX];          // 2 KB

    const int tid  = threadIdx.x;
    const int w    = tid >> 6;
    const int lane = tid & 63;
    const int k    = lane & 31;
    const int h    = lane >> 5;
    const int hi8  = h * 8;
    const int bb   = blockIdx.x * 8 + w * 2;
    const int b    = bb + h;
    const bool hi16 = (lane & 16) != 0;
    const float LOG2E = 1.4426950408889634f;

    ytL[w][0][lane] = yt[(size_t)bb * NRX + lane];
    ytL[w][1][lane] = yt[(size_t)bb * NRX + NRX + lane];

    // delta in exp2 domain; tau natural
    float dreg = 0.f, treg = 1.f;
    if (lane < niter) { dreg = delta[lane] * LOG2E; treg = fabsf(taui[lane + 1]); }

    float sig2 = sigmat0[b];
    sig2 *= sig2;

    float yhp0 = 0.f, yhp1 = 0.f;

    // ---- Phase 1: per batch s: MFMA HH (f[8] staging in flight) ----
    #pragma unroll
    for (int s = 0; s < 2; ++s) {
        f32x16 acc;
        #pragma unroll
        for (int j = 0; j < 16; ++j) acc[j] = 0.f;

        const float* Hb = Ht + ((size_t)(bb + s)) * (NRX * KSYM);
        #pragma unroll
        for (int c = 0; c < 4; ++c) {
            const float* base = Hb + (c * 16 + hi8) * KSYM + k;
            float f[8];
            #pragma unroll
            for (int e = 0; e < 8; ++e) f[e] = base[e * KSYM];

            float4 ya = *reinterpret_cast<const float4*>(&ytL[w][s][c * 16 + hi8]);
            float4 yb = *reinterpret_cast<const float4*>(&ytL[w][s][c * 16 + hi8 + 4]);
            float yp = (s == 0) ? yhp0 : yhp1;
            yp = fmaf(ya.x, f[0], yp); yp = fmaf(ya.y, f[1], yp);
            yp = fmaf(ya.z, f[2], yp); yp = fmaf(ya.w, f[3], yp);
            yp = fmaf(yb.x, f[4], yp); yp = fmaf(yb.y, f[5], yp);
            yp = fmaf(yb.z, f[6], yp); yp = fmaf(yb.w, f[7], yp);
            if (s == 0) yhp0 = yp; else yhp1 = yp;

            FragU hiF, loF;
            #pragma unroll
            for (int p = 0; p < 4; ++p) {
                unsigned hp = cvt_pk_bf16(f[2*p], f[2*p+1]);
                float h0 = __uint_as_float(hp << 16);
                float h1 = __uint_as_float(hp & 0xffff0000u);
                loF.u[p] = cvt_pk_bf16(f[2*p] - h0, f[2*p+1] - h1);
                hiF.u[p] = hp;
            }
            acc = __builtin_amdgcn_mfma_f32_32x32x16_bf16(hiF.s, hiF.s, acc, 0, 0, 0);
            acc = __builtin_amdgcn_mfma_f32_32x32x16_bf16(hiF.s, loF.s, acc, 0, 0, 0);
            acc = __builtin_amdgcn_mfma_f32_32x32x16_bf16(loF.s, hiF.s, acc, 0, 0, 0);
        }

        // acc -> f16 LDS (0.5-prefolded). C/D layout: col=k, row=(j&3)+8*(j>>2)+4*h
        #pragma unroll
        for (int j = 0; j < 16; ++j) {
            int row = (j & 3) + 8 * (j >> 2) + 4 * h;
            hh16[w][s][row * 32 + k] = (_Float16)(0.5f * acc[j]);
        }
    }

    // ---- Phase 2: UNIFORM gather from region h (same DPP_ROR as loop) ----
    int own_pk[16];
    {
        const int low4 = k & 15;
        const unsigned short* rp =
            reinterpret_cast<const unsigned short*>(&hh16[w][h][0]) + k * 32;
        own_pk[0] = (int)rp[k] | ((int)rp[k ^ 16] << 16);
        #define GATH(J) { \
            int idx; DPP_ROR(idx, low4, J); \
            int cA = (k & 16) | idx; \
            own_pk[J] = (int)rp[cA] | ((int)rp[cA ^ 16] << 16); }
        GATH(1)  GATH(2)  GATH(3)  GATH(4)  GATH(5)
        GATH(6)  GATH(7)  GATH(8)  GATH(9)  GATH(10)
        GATH(11) GATH(12) GATH(13) GATH(14) GATH(15)
        #undef GATH
    }

    float yh0 = yhp0 + __shfl_xor(yhp0, 32, 64);
    float yh1 = yhp1 + __shfl_xor(yhp1, 32, 64);
    float yh  = 0.5f * (h ? yh1 : yh0);   // pre-halved to match own_pk scale

    // ---- Phase 3: iterations (unrolled x2; e's prefetched) ----
    float tau = fabsf(taui[0]);
    float Gl0 = 0.f, Gl1 = 0.f;           // G * log2e
    float xt = 0.f;
    float e0 = 1.f, e1 = 1.f;             // exp2(-Gl) for the upcoming iter

    #define ITER(I) {                                                          \
        float d2       = readlane_f(dreg, (I));                                \
        float tau_next = readlane_f(treg, (I));                                \
        float xts = xor16_f(xt, hi16);                                         \
        int xpk = cvt_pk_f16(xt, xts);                                         \
        float a0 = -yh, a1 = 0.f, a2 = 0.f, a3 = 0.f;                          \
        a0 = dot2_f16(own_pk[0], xpk, a0);                                     \
        STEP(1)  STEP(2)  STEP(3)  STEP(4)  STEP(5)                            \
        STEP(6)  STEP(7)  STEP(8)  STEP(9)  STEP(10)                           \
        STEP(11) STEP(12) STEP(13) STEP(14) STEP(15)                           \
        float r = (a0 + a1) + (a2 + a3);                                       \
        float t  = fmaf(-xt, xt, 1.0f);                                        \
        float p  = tau * t * r;                                                \
        float g0 = fmaf(sig2, 1.f - e0, -p);                                   \
        float g1 = fmaf(sig2, 1.f - e1,  p);                                   \
        Gl0 = fmaf(-d2, g0, Gl0);                                              \
        Gl1 = fmaf(-d2, g1, Gl1);                                              \
        e0 = exp2_fast(-Gl0);     /* prefetch for NEXT iter */                 \
        e1 = exp2_fast(-Gl1);                                                  \
        tau = tau_next;                                                        \
        float z2 = tau * (Gl1 - Gl0);                                          \
        float ez = exp2_fast(-fabsf(z2));                                      \
        float sg = __builtin_amdgcn_rcpf(1.f + ez);                            \
        float m  = (1.f - ez) * sg;                                            \
        xt = __builtin_copysignf(m, z2); }
    #define STEP(J) {                                                          \
        int xr; DPP_ROR(xr, xpk, J);                                           \
        float& aa = ((J) & 3) == 0 ? a0 : ((J) & 3) == 1 ? a1                  \
                   : ((J) & 3) == 2 ? a2 : a3;                                 \
        aa = dot2_f16(own_pk[J], xr, aa); }

    int i = 0;
    for (; i + 1 < niter; i += 2) { ITER(i); ITER(i + 1); }
    if (i < niter) { ITER(i); }
    #undef STEP
    #undef ITER

    // ---- outputs: ft1 = (1+xt)/2, ft0 = (1-xt)/2 ----
    float ft1 = fmaf(0.5f, xt, 0.5f);
    float ft0 = 1.f - ft1;
    float2 f2 = make_float2(ft0, ft1);
    reinterpret_cast<float2*>(out_ft)[(size_t)b * KSYM + k] = f2;
    out_xt[(size_t)b * KSYM + k] = xt;
}

extern "C" void kernel_launch(void* const* d_in, const int* in_sizes, int n_in,
                              void* d_out, int out_size, void* d_ws, size_t ws_size,
                              hipStream_t stream) {
    const float* yt    = (const float*)d_in[0];
    const float* Ht    = (const float*)d_in[1];
    const float* sg    = (const float*)d_in[2];
    const float* taui  = (const float*)d_in[3];
    const float* delta = (const float*)d_in[4];
    int B     = in_sizes[2];
    int niter = in_sizes[4];
    float* out    = (float*)d_out;
    float* out_ft = out;
    float* out_xt = out + (size_t)B * 64;

    dim3 grid(B / 8), block(256);
    hipLaunchKernelGGL(cmdnet_kernel, grid, block, 0, stream,
                       yt, Ht, sg, taui, delta, out_ft, out_xt, niter);
}